// Round 1
// baseline (124.115 us; speedup 1.0000x reference)
//
#include <hip/hip_runtime.h>

#define HDIM 128

typedef short bf16x8 __attribute__((ext_vector_type(8)));
typedef float f32x4 __attribute__((ext_vector_type(4)));

// fp32 -> bf16 round-to-nearest-even, returned as raw short
__device__ __forceinline__ short f2bf(float f) {
    unsigned u = __builtin_bit_cast(unsigned, f);
    u += 0x7fffu + ((u >> 16) & 1u);
    return (short)(u >> 16);
}

// B-fragment read from swizzled WT[n][k] LDS image (16B, contiguous 8 k at column n)
__device__ __forceinline__ bf16x8 ldB(const short* sW, int n, int chunk) {
    return *(const bf16x8*)(sW + n * HDIM + ((chunk ^ (n & 7)) << 3));
}

// A-fragment: 8 consecutive k of x[src]*x[dst], fp32 product then one bf16 round
__device__ __forceinline__ bf16x8 gatherA(const float* xs, const float* xd, int k0) {
    float4 a0 = *(const float4*)(xs + k0);
    float4 a1 = *(const float4*)(xs + k0 + 4);
    float4 c0 = *(const float4*)(xd + k0);
    float4 c1 = *(const float4*)(xd + k0 + 4);
    bf16x8 r = { f2bf(a0.x * c0.x), f2bf(a0.y * c0.y), f2bf(a0.z * c0.z), f2bf(a0.w * c0.w),
                 f2bf(a1.x * c1.x), f2bf(a1.y * c1.y), f2bf(a1.z * c1.z), f2bf(a1.w * c1.w) };
    return r;
}

__global__ __launch_bounds__(256, 2)
void edge_mlp_kernel(const float* __restrict__ x,
                     const int* __restrict__ src,
                     const int* __restrict__ dst,
                     const float* __restrict__ W1, const float* __restrict__ b1,
                     const float* __restrict__ W2, const float* __restrict__ b2,
                     const float* __restrict__ W3, const float* __restrict__ b3,
                     float* __restrict__ out, int E)
{
    // 80 KB total -> 2 blocks/CU (gfx950 allows >64KB per workgroup)
    __shared__ short sW1[HDIM * HDIM];      // WT1[n][k] bf16, chunk-swizzled (32 KB)
    __shared__ short sW2[HDIM * HDIM];      // WT2[n][k] bf16, chunk-swizzled (32 KB)
    __shared__ short sH1[4][32 * 64];       // per-wave H1 transpose staging, one k-half (16 KB)

    const int tid = threadIdx.x;

    // ---- stage weights: global fp32 [k][n] -> LDS bf16 WT[n][k], swizzled ----
    {
        const int n  = tid & 127;
        const int kh = tid >> 7;            // 0 or 1
        for (int c = 0; c < 8; ++c) {
            const int kc = kh * 8 + c;      // 16B chunk index, 0..15
            const int k0 = kc * 8;
            short v1[8], v2[8];
            #pragma unroll
            for (int j = 0; j < 8; ++j) {
                v1[j] = f2bf(W1[(k0 + j) * HDIM + n]);
                v2[j] = f2bf(W2[(k0 + j) * HDIM + n]);
            }
            const int off = n * HDIM + ((kc ^ (n & 7)) << 3);
            bf16x8 t1 = { v1[0], v1[1], v1[2], v1[3], v1[4], v1[5], v1[6], v1[7] };
            bf16x8 t2 = { v2[0], v2[1], v2[2], v2[3], v2[4], v2[5], v2[6], v2[7] };
            *(bf16x8*)(sW1 + off) = t1;
            *(bf16x8*)(sW2 + off) = t2;
        }
    }
    __syncthreads();   // only barrier in the kernel; weights are read-only afterwards

    const int w    = tid >> 6;      // wave 0..3
    const int lane = tid & 63;
    const int g    = lane >> 4;     // 16-lane group 0..3
    const int e16  = lane & 15;
    short* myH1 = &sH1[w][0];

    // per-lane hoisted bias / W3 values (column = 16*nt + e16)
    float b1v[8], b2v[8], w3v[8];
    #pragma unroll
    for (int nt = 0; nt < 8; ++nt) {
        b1v[nt] = b1[nt * 16 + e16];
        b2v[nt] = b2[nt * 16 + e16];
        w3v[nt] = W3[nt * 16 + e16];
    }
    const float b3s = b3[0];

    const int ntiles = (E + 127) >> 7;   // 128 edges per block-tile
    for (int tile = blockIdx.x; tile < ntiles; tile += gridDim.x) {
        const int base = (tile << 7) + w * 32;   // this wave's 32 edges
        const int e0 = base + e16;
        const int e1 = base + 16 + e16;
        const int ce0 = e0 < E ? e0 : 0;
        const int ce1 = e1 < E ? e1 : 0;
        const float* xs0 = x + (size_t)src[ce0] * HDIM;
        const float* xd0 = x + (size_t)dst[ce0] * HDIM;
        const float* xs1 = x + (size_t)src[ce1] * HDIM;
        const float* xd1 = x + (size_t)dst[ce1] * HDIM;

        // ---------- GEMM1: H1 = relu(G @ W1 + b1), G built in-register ----------
        f32x4 acc[2][8];
        #pragma unroll
        for (int nt = 0; nt < 8; ++nt) {
            f32x4 iv = { b1v[nt], b1v[nt], b1v[nt], b1v[nt] };
            acc[0][nt] = iv;
            acc[1][nt] = iv;
        }
        #pragma unroll
        for (int t = 0; t < 4; ++t) {
            const int k0 = t * 32 + g * 8;
            bf16x8 a0 = gatherA(xs0, xd0, k0);
            bf16x8 a1 = gatherA(xs1, xd1, k0);
            #pragma unroll
            for (int nt = 0; nt < 8; ++nt) {
                bf16x8 bb = ldB(sW1, nt * 16 + e16, t * 4 + g);
                acc[0][nt] = __builtin_amdgcn_mfma_f32_16x16x32_bf16(a0, bb, acc[0][nt], 0, 0, 0);
                acc[1][nt] = __builtin_amdgcn_mfma_f32_16x16x32_bf16(a1, bb, acc[1][nt], 0, 0, 0);
            }
        }

        // ---------- GEMM2: H2 = relu(H1 @ W2 + b2), H1 staged per-wave in 2 k-halves ----------
        f32x4 acc2[2][8];
        #pragma unroll
        for (int nt = 0; nt < 8; ++nt) {
            f32x4 iv = { b2v[nt], b2v[nt], b2v[nt], b2v[nt] };
            acc2[0][nt] = iv;
            acc2[1][nt] = iv;
        }
        #pragma unroll
        for (int khf = 0; khf < 2; ++khf) {
            // write relu(H1) columns 64*khf .. +63 transposed into myH1[e][kk] (swizzled)
            #pragma unroll
            for (int ntl = 0; ntl < 4; ++ntl) {
                const int nt = khf * 4 + ntl;
                #pragma unroll
                for (int mt = 0; mt < 2; ++mt) {
                    #pragma unroll
                    for (int r = 0; r < 4; ++r) {
                        const int e  = mt * 16 + g * 4 + r;   // edge-row within wave tile
                        const int kk = ntl * 16 + e16;        // k within this half
                        float v = acc[mt][nt][r];
                        v = v > 0.0f ? v : 0.0f;
                        myH1[e * 64 + (((kk >> 3) ^ (e & 7)) << 3) + (kk & 7)] = f2bf(v);
                    }
                }
            }
            // consume this half: k-steps t2 = 2*khf + {0,1}
            #pragma unroll
            for (int tl = 0; tl < 2; ++tl) {
                const int ck = tl * 4 + g;                    // chunk within half
                bf16x8 a0 = *(const bf16x8*)(myH1 + e16 * 64 + ((ck ^ (e16 & 7)) << 3));
                bf16x8 a1 = *(const bf16x8*)(myH1 + (e16 + 16) * 64 + ((ck ^ ((e16 + 16) & 7)) << 3));
                const int t2 = khf * 2 + tl;
                #pragma unroll
                for (int nt = 0; nt < 8; ++nt) {
                    bf16x8 bb = ldB(sW2, nt * 16 + e16, t2 * 4 + g);
                    acc2[0][nt] = __builtin_amdgcn_mfma_f32_16x16x32_bf16(a0, bb, acc2[0][nt], 0, 0, 0);
                    acc2[1][nt] = __builtin_amdgcn_mfma_f32_16x16x32_bf16(a1, bb, acc2[1][nt], 0, 0, 0);
                }
            }
        }

        // ---------- final: out = relu(H2) @ W3 + b3 (fp32), 16-lane butterfly ----------
        #pragma unroll
        for (int mt = 0; mt < 2; ++mt) {
            float p0 = 0.f, p1 = 0.f, p2 = 0.f, p3 = 0.f;
            #pragma unroll
            for (int nt = 0; nt < 8; ++nt) {
                f32x4 v = acc2[mt][nt];
                float r0 = v[0] > 0.f ? v[0] : 0.f;
                float r1 = v[1] > 0.f ? v[1] : 0.f;
                float r2 = v[2] > 0.f ? v[2] : 0.f;
                float r3 = v[3] > 0.f ? v[3] : 0.f;
                p0 += r0 * w3v[nt];
                p1 += r1 * w3v[nt];
                p2 += r2 * w3v[nt];
                p3 += r3 * w3v[nt];
            }
            #pragma unroll
            for (int off = 1; off < 16; off <<= 1) {
                p0 += __shfl_xor(p0, off);
                p1 += __shfl_xor(p1, off);
                p2 += __shfl_xor(p2, off);
                p3 += __shfl_xor(p3, off);
            }
            if (e16 == 0) {
                const int eb = base + mt * 16 + g * 4;   // rows 4g..4g+3 of this sub-tile
                if (eb + 0 < E) out[eb + 0] = p0 + b3s;
                if (eb + 1 < E) out[eb + 1] = p1 + b3s;
                if (eb + 2 < E) out[eb + 2] = p2 + b3s;
                if (eb + 3 < E) out[eb + 3] = p3 + b3s;
            }
        }
    }
}

extern "C" void kernel_launch(void* const* d_in, const int* in_sizes, int n_in,
                              void* d_out, int out_size, void* d_ws, size_t ws_size,
                              hipStream_t stream) {
    const float* x   = (const float*)d_in[0];
    const int*   src = (const int*)d_in[1];
    const int*   dst = (const int*)d_in[2];
    const float* W1  = (const float*)d_in[3];
    const float* b1  = (const float*)d_in[4];
    const float* W2  = (const float*)d_in[5];
    const float* b2  = (const float*)d_in[6];
    const float* W3  = (const float*)d_in[7];
    const float* b3  = (const float*)d_in[8];
    float* out = (float*)d_out;

    const int E = in_sizes[1];
    const int ntiles = (E + 127) >> 7;
    const int grid = ntiles < 512 ? ntiles : 512;   // persistent: 2 blocks/CU x 256 CU

    hipLaunchKernelGGL(edge_mlp_kernel, dim3(grid), dim3(256), 0, stream,
                       x, src, dst, W1, b1, W2, b2, W3, b3, out, E);
}